// Round 1
// baseline (199.391 us; speedup 1.0000x reference)
//
#include <hip/hip_runtime.h>

// PointsRasterizer: naive per-pixel gather over all points.
// One thread per pixel; register-resident top-K (K=8) insertion sort by z.
// Outputs written as float32: [idx | zbuf | dists], each N*S*S*K floats.

constexpr int S = 128;       // IMAGE_SIZE
constexpr int K = 8;         // POINTS_PER_PIXEL
constexpr float R2 = 0.01f * 0.01f;
constexpr float BIGF = 1e10f;

__global__ __launch_bounds__(64)
void raster_naive(const float* __restrict__ pts, float* __restrict__ out,
                  int P, int npix, int chunk) {
    const int pid = blockIdx.x * 64 + threadIdx.x;
    if (pid >= npix) return;

    const int n = pid >> 14;             // pid / (S*S), S*S = 16384
    const int h = (pid >> 7) & (S - 1);
    const int w = pid & (S - 1);

    // ndc = 1 - 2*(i+0.5)/S = 1 - (2i+1)/128  (exact in fp32)
    const float ndcy = 1.0f - (float)(2 * h + 1) * 0.0078125f;
    const float ndcx = 1.0f - (float)(2 * w + 1) * 0.0078125f;

    float zk[K];   // ascending z of selected points
    float dk[K];   // squared distances of selected points
    int   ik[K];   // point indices
#pragma unroll
    for (int k = 0; k < K; ++k) { zk[k] = BIGF; dk[k] = -1.0f; ik[k] = -1; }

    const float* __restrict__ b = pts + (size_t)n * P * 3;

#pragma unroll 4
    for (int p = 0; p < P; ++p) {
        const float x = b[3 * p + 0];
        const float y = b[3 * p + 1];
        const float z = b[3 * p + 2];
        const float dx = ndcx - x;
        const float dy = ndcy - y;
        const float dx2 = dx * dx;
        const float dy2 = dy * dy;
        const float d2 = dy2 + dx2;
        // hit test; z < zk[K-1] strict keeps top_k's stable tie-break
        if (d2 < R2 && z > 0.0f && z < zk[K - 1]) {
            float zi = z, di = d2;
            int pi = p;
#pragma unroll
            for (int k = 0; k < K; ++k) {
                if (zi < zk[k]) {
                    float t;
                    t = zk[k]; zk[k] = zi; zi = t;
                    t = dk[k]; dk[k] = di; di = t;
                    int ti = ik[k]; ik[k] = pi; pi = ti;
                }
            }
        }
    }

    // Mask zbuf for invalid slots (ik/dk already -1 by init).
    float zb[K];
#pragma unroll
    for (int k = 0; k < K; ++k) zb[k] = (zk[k] < BIGF) ? zk[k] : -1.0f;

    // Write as float32, 2x float4 per section. chunk = npix*K floats.
    float4* o = reinterpret_cast<float4*>(out);
    const int c4 = chunk >> 2;      // float4 stride between sections
    const int q = pid * 2;          // float4 index within a section

    o[q]     = make_float4((float)ik[0], (float)ik[1], (float)ik[2], (float)ik[3]);
    o[q + 1] = make_float4((float)ik[4], (float)ik[5], (float)ik[6], (float)ik[7]);

    o[c4 + q]     = make_float4(zb[0], zb[1], zb[2], zb[3]);
    o[c4 + q + 1] = make_float4(zb[4], zb[5], zb[6], zb[7]);

    o[2 * c4 + q]     = make_float4(dk[0], dk[1], dk[2], dk[3]);
    o[2 * c4 + q + 1] = make_float4(dk[4], dk[5], dk[6], dk[7]);
}

extern "C" void kernel_launch(void* const* d_in, const int* in_sizes, int n_in,
                              void* d_out, int out_size, void* d_ws, size_t ws_size,
                              hipStream_t stream) {
    const float* pts = (const float*)d_in[0];
    float* out = (float*)d_out;

    const int P = 2048;
    const int N = in_sizes[0] / (3 * P);   // = 2
    const int npix = N * S * S;            // 32768
    const int chunk = npix * K;            // 262144 floats per output section

    const int block = 64;
    const int grid = (npix + block - 1) / block;   // 512
    hipLaunchKernelGGL(raster_naive, dim3(grid), dim3(block), 0, stream,
                       pts, out, P, npix, chunk);
}

// Round 2
// 20.016 us; speedup vs baseline: 9.9618x; 9.9618x over previous
//
#include <hip/hip_runtime.h>

// PointsRasterizer, tiled: one block per 16x16 pixel tile.
// Phase 1: block filters all P points against tile bbox (+slack), compacts
//          survivors into LDS via atomicAdd (order nondeterministic).
// Phase 2: each thread (= 1 pixel) tests survivors, keeps top-K=8 by
//          lexicographic (z, idx) -> arrival-order independent, matches
//          jax.lax.top_k stable tie-breaking.
// Outputs float32: [idx | zbuf | dists], each N*S*S*K floats.

constexpr int S = 128;          // IMAGE_SIZE
constexpr int K = 8;            // POINTS_PER_PIXEL
constexpr float R2 = 0.01f * 0.01f;
constexpr float RF = 0.0102f;   // bbox filter radius with slack
constexpr float BIGF = 1e10f;
constexpr int MAXP = 2048;      // LDS capacity (== P)

__global__ __launch_bounds__(256)
void raster_tiled(const float* __restrict__ pts, float* __restrict__ out,
                  int P, int npix) {
    __shared__ float4 sp[MAXP];
    __shared__ int scnt;

    const int tid = threadIdx.x;
    const int n    = blockIdx.x >> 6;       // image
    const int tile = blockIdx.x & 63;       // 8x8 tiles of 16x16 pixels
    const int tr = tile >> 3, tc = tile & 7;
    const int h = tr * 16 + (tid >> 4);
    const int w = tc * 16 + (tid & 15);

    // ndc = 1 - (2i+1)/128, exact in fp32
    const float ndcy = 1.0f - (float)(2 * h + 1) * 0.0078125f;
    const float ndcx = 1.0f - (float)(2 * w + 1) * 0.0078125f;

    // tile ndc bounds (ndc decreases with pixel index)
    const float xhi = 1.0f - (float)(2 * (tc * 16) + 1)      * 0.0078125f + RF;
    const float xlo = 1.0f - (float)(2 * (tc * 16 + 15) + 1) * 0.0078125f - RF;
    const float yhi = 1.0f - (float)(2 * (tr * 16) + 1)      * 0.0078125f + RF;
    const float ylo = 1.0f - (float)(2 * (tr * 16 + 15) + 1) * 0.0078125f - RF;

    if (tid == 0) scnt = 0;
    __syncthreads();

    // ---- Phase 1: filter + compact into LDS ----
    const float* __restrict__ b = pts + (size_t)n * P * 3;
    for (int c = 0; c < P; c += 256) {
        const int p = c + tid;
        const float x = b[3 * p + 0];
        const float y = b[3 * p + 1];
        const float z = b[3 * p + 2];
        if (x > xlo && x < xhi && y > ylo && y < yhi && z > 0.0f) {
            const int pos = atomicAdd(&scnt, 1);
            if (pos < MAXP) sp[pos] = make_float4(x, y, z, __int_as_float(p));
        }
    }
    __syncthreads();
    const int cnt = (scnt < MAXP) ? scnt : MAXP;

    // ---- Phase 2: per-pixel top-K over survivors ----
    float zk[K];   // ascending (z, idx)
    float dk[K];
    int   ik[K];
#pragma unroll
    for (int k = 0; k < K; ++k) { zk[k] = BIGF; dk[k] = -1.0f; ik[k] = 0x7fffffff; }

#pragma unroll 2
    for (int j = 0; j < cnt; ++j) {
        const float4 q = sp[j];           // broadcast read, conflict-free
        const float dx = ndcx - q.x;
        const float dy = ndcy - q.y;
        const float dx2 = dx * dx;
        const float dy2 = dy * dy;
        const float d2 = dy2 + dx2;       // identical expression to ref/r1
        if (d2 < R2 && q.z > 0.0f) {
            const int pi = __float_as_int(q.w);
            // accept if (z,idx) < (zk[K-1], ik[K-1]) lexicographic
            if (q.z < zk[K - 1] || (q.z == zk[K - 1] && pi < ik[K - 1])) {
                float zi = q.z, di = d2;
                int   pj = pi;
#pragma unroll
                for (int k = 0; k < K; ++k) {
                    const bool lt = (zi < zk[k]) || (zi == zk[k] && pj < ik[k]);
                    if (lt) {
                        float t;
                        t = zk[k]; zk[k] = zi; zi = t;
                        t = dk[k]; dk[k] = di; di = t;
                        int ti = ik[k]; ik[k] = pj; pj = ti;
                    }
                }
            }
        }
    }

    // mask invalid slots
    float zb[K];
    float ib[K];
#pragma unroll
    for (int k = 0; k < K; ++k) {
        const bool v = zk[k] < BIGF;
        zb[k] = v ? zk[k] : -1.0f;
        ib[k] = v ? (float)ik[k] : -1.0f;
    }

    // ---- write float32 outputs: [idx | zbuf | dists] ----
    const int pid = n * (S * S) + h * S + w;
    float4* o = reinterpret_cast<float4*>(out);
    const int c4 = (npix * K) >> 2;   // float4 stride between sections
    const int q = pid * 2;

    o[q]     = make_float4(ib[0], ib[1], ib[2], ib[3]);
    o[q + 1] = make_float4(ib[4], ib[5], ib[6], ib[7]);

    o[c4 + q]     = make_float4(zb[0], zb[1], zb[2], zb[3]);
    o[c4 + q + 1] = make_float4(zb[4], zb[5], zb[6], zb[7]);

    o[2 * c4 + q]     = make_float4(dk[0], dk[1], dk[2], dk[3]);
    o[2 * c4 + q + 1] = make_float4(dk[4], dk[5], dk[6], dk[7]);
}

extern "C" void kernel_launch(void* const* d_in, const int* in_sizes, int n_in,
                              void* d_out, int out_size, void* d_ws, size_t ws_size,
                              hipStream_t stream) {
    const float* pts = (const float*)d_in[0];
    float* out = (float*)d_out;

    const int P = 2048;
    const int N = in_sizes[0] / (3 * P);   // = 2
    const int npix = N * S * S;            // 32768

    const int grid = N * 64;               // 64 tiles per image
    hipLaunchKernelGGL(raster_tiled, dim3(grid), dim3(256), 0, stream,
                       pts, out, P, npix);
}

// Round 3
// 19.531 us; speedup vs baseline: 10.2092x; 1.0248x over previous
//
#include <hip/hip_runtime.h>

// PointsRasterizer, tiled: one block per 8x16 pixel tile (256 blocks = 1/CU).
// Phase 1: 128 threads filter all 2048 points against tile bbox (+slack),
//          compact survivors into LDS via atomicAdd (order nondeterministic).
// Phase 2: each thread (= 1 pixel) tests survivors, keeps top-K=8 by
//          lexicographic (z, idx) -> arrival-order independent, matches
//          jax.lax.top_k stable tie-breaking.
// Outputs float32: [idx | zbuf | dists], each N*S*S*K floats.

constexpr int S = 128;          // IMAGE_SIZE
constexpr int K = 8;            // POINTS_PER_PIXEL
constexpr int P = 2048;         // points per image (fixed)
constexpr float R2 = 0.01f * 0.01f;
constexpr float RF = 0.0102f;   // bbox filter radius with slack
constexpr float BIGF = 1e10f;
constexpr int MAXP = 2048;      // LDS capacity (== P, always safe)

constexpr int TH = 8;           // tile rows
constexpr int TW = 16;          // tile cols
constexpr int BLK = TH * TW;    // 128 threads

__global__ __launch_bounds__(BLK)
void raster_tiled(const float* __restrict__ pts, float* __restrict__ out,
                  int npix) {
    __shared__ float4 sp[MAXP];
    __shared__ int scnt;

    const int tid  = threadIdx.x;
    const int n    = blockIdx.x >> 7;        // image
    const int tile = blockIdx.x & 127;       // 16x8 tiles of 8x16 pixels
    const int tr = tile >> 3, tc = tile & 7;
    const int h = tr * TH + (tid >> 4);
    const int w = tc * TW + (tid & 15);

    // ndc = 1 - (2i+1)/128, exact in fp32
    const float ndcy = 1.0f - (float)(2 * h + 1) * 0.0078125f;
    const float ndcx = 1.0f - (float)(2 * w + 1) * 0.0078125f;

    // tile ndc bounds (ndc decreases with pixel index)
    const float xhi = 1.0f - (float)(2 * (tc * TW) + 1)          * 0.0078125f + RF;
    const float xlo = 1.0f - (float)(2 * (tc * TW + TW - 1) + 1) * 0.0078125f - RF;
    const float yhi = 1.0f - (float)(2 * (tr * TH) + 1)          * 0.0078125f + RF;
    const float ylo = 1.0f - (float)(2 * (tr * TH + TH - 1) + 1) * 0.0078125f - RF;

    if (tid == 0) scnt = 0;
    __syncthreads();

    // ---- Phase 1: filter + compact into LDS (16 iters, unrolled 4) ----
    const float* __restrict__ b = pts + (size_t)n * P * 3;
#pragma unroll 4
    for (int c = 0; c < P; c += BLK) {
        const int p = c + tid;
        const float x = b[3 * p + 0];
        const float y = b[3 * p + 1];
        const float z = b[3 * p + 2];
        if (x > xlo && x < xhi && y > ylo && y < yhi && z > 0.0f) {
            const int pos = atomicAdd(&scnt, 1);
            if (pos < MAXP) sp[pos] = make_float4(x, y, z, __int_as_float(p));
        }
    }
    __syncthreads();
    const int cnt = (scnt < MAXP) ? scnt : MAXP;

    // ---- Phase 2: per-pixel top-K over survivors ----
    float zk[K];   // ascending (z, idx)
    float dk[K];
    int   ik[K];
#pragma unroll
    for (int k = 0; k < K; ++k) { zk[k] = BIGF; dk[k] = -1.0f; ik[k] = 0x7fffffff; }

#pragma unroll 2
    for (int j = 0; j < cnt; ++j) {
        const float4 q = sp[j];           // broadcast read, conflict-free
        const float dx = ndcx - q.x;
        const float dy = ndcy - q.y;
        const float dx2 = dx * dx;
        const float dy2 = dy * dy;
        const float d2 = dy2 + dx2;       // identical expression to ref/r1
        if (d2 < R2 && q.z > 0.0f) {
            const int pi = __float_as_int(q.w);
            // accept if (z,idx) < (zk[K-1], ik[K-1]) lexicographic
            if (q.z < zk[K - 1] || (q.z == zk[K - 1] && pi < ik[K - 1])) {
                float zi = q.z, di = d2;
                int   pj = pi;
#pragma unroll
                for (int k = 0; k < K; ++k) {
                    const bool lt = (zi < zk[k]) || (zi == zk[k] && pj < ik[k]);
                    if (lt) {
                        float t;
                        t = zk[k]; zk[k] = zi; zi = t;
                        t = dk[k]; dk[k] = di; di = t;
                        int ti = ik[k]; ik[k] = pj; pj = ti;
                    }
                }
            }
        }
    }

    // mask invalid slots
    float zb[K];
    float ib[K];
#pragma unroll
    for (int k = 0; k < K; ++k) {
        const bool v = zk[k] < BIGF;
        zb[k] = v ? zk[k] : -1.0f;
        ib[k] = v ? (float)ik[k] : -1.0f;
    }

    // ---- write float32 outputs: [idx | zbuf | dists] ----
    const int pid = n * (S * S) + h * S + w;
    float4* o = reinterpret_cast<float4*>(out);
    const int c4 = (npix * K) >> 2;   // float4 stride between sections
    const int q = pid * 2;

    o[q]     = make_float4(ib[0], ib[1], ib[2], ib[3]);
    o[q + 1] = make_float4(ib[4], ib[5], ib[6], ib[7]);

    o[c4 + q]     = make_float4(zb[0], zb[1], zb[2], zb[3]);
    o[c4 + q + 1] = make_float4(zb[4], zb[5], zb[6], zb[7]);

    o[2 * c4 + q]     = make_float4(dk[0], dk[1], dk[2], dk[3]);
    o[2 * c4 + q + 1] = make_float4(dk[4], dk[5], dk[6], dk[7]);
}

extern "C" void kernel_launch(void* const* d_in, const int* in_sizes, int n_in,
                              void* d_out, int out_size, void* d_ws, size_t ws_size,
                              hipStream_t stream) {
    const float* pts = (const float*)d_in[0];
    float* out = (float*)d_out;

    const int N = in_sizes[0] / (3 * P);   // = 2
    const int npix = N * S * S;            // 32768

    const int grid = N * 128;              // 128 tiles per image -> 256 blocks
    hipLaunchKernelGGL(raster_tiled, dim3(grid), dim3(BLK), 0, stream,
                       pts, out, npix);
}

// Round 4
// 18.093 us; speedup vs baseline: 11.0204x; 1.0795x over previous
//
#include <hip/hip_runtime.h>

// PointsRasterizer, tiled + paired: one block per 8x16 pixel tile, 256 threads.
// Phase 1: 256 threads filter all 2048 points (8 iters, fully unrolled)
//          against tile bbox (+slack), compact into LDS via atomicAdd.
// Phase 2: TWO threads per pixel (same-wave pair tid, tid^1) each scan half
//          the survivors keeping a register top-K=8 by lexicographic (z,idx)
//          (arrival-order independent, matches jax.lax.top_k stable ties),
//          then exchange via __shfl_xor and merge with the same insertion.
// Outputs float32: [idx | zbuf | dists], each N*S*S*K floats.

constexpr int S = 128;          // IMAGE_SIZE
constexpr int K = 8;            // POINTS_PER_PIXEL
constexpr int P = 2048;         // points per image (fixed)
constexpr float R2 = 0.01f * 0.01f;
constexpr float RF = 0.0102f;   // bbox filter radius with slack
constexpr float BIGF = 1e10f;
constexpr int MAXP = 2048;      // LDS capacity (== P, always safe)

constexpr int TH = 8;           // tile rows
constexpr int TW = 16;          // tile cols
constexpr int BLK = 256;        // 2 threads per pixel

__global__ __launch_bounds__(BLK)
void raster_paired(const float* __restrict__ pts, float* __restrict__ out,
                   int npix) {
    __shared__ float4 sp[MAXP];
    __shared__ int scnt;

    const int tid  = threadIdx.x;
    const int n    = blockIdx.x >> 7;        // image
    const int tile = blockIdx.x & 127;       // 16x8 tiles of 8x16 pixels
    const int tr = tile >> 3, tc = tile & 7;
    const int pix  = tid >> 1;               // 0..127 pixel within tile
    const int half = tid & 1;                // which half of survivor list
    const int h = tr * TH + (pix >> 4);
    const int w = tc * TW + (pix & 15);

    // ndc = 1 - (2i+1)/128, exact in fp32
    const float ndcy = 1.0f - (float)(2 * h + 1) * 0.0078125f;
    const float ndcx = 1.0f - (float)(2 * w + 1) * 0.0078125f;

    // tile ndc bounds (ndc decreases with pixel index)
    const float xhi = 1.0f - (float)(2 * (tc * TW) + 1)          * 0.0078125f + RF;
    const float xlo = 1.0f - (float)(2 * (tc * TW + TW - 1) + 1) * 0.0078125f - RF;
    const float yhi = 1.0f - (float)(2 * (tr * TH) + 1)          * 0.0078125f + RF;
    const float ylo = 1.0f - (float)(2 * (tr * TH + TH - 1) + 1) * 0.0078125f - RF;

    if (tid == 0) scnt = 0;
    __syncthreads();

    // ---- Phase 1: filter + compact into LDS (8 iters, fully unrolled) ----
    const float* __restrict__ b = pts + (size_t)n * P * 3;
#pragma unroll
    for (int c = 0; c < P; c += BLK) {
        const int p = c + tid;
        const float x = b[3 * p + 0];
        const float y = b[3 * p + 1];
        const float z = b[3 * p + 2];
        if (x > xlo && x < xhi && y > ylo && y < yhi && z > 0.0f) {
            const int pos = atomicAdd(&scnt, 1);
            if (pos < MAXP) sp[pos] = make_float4(x, y, z, __int_as_float(p));
        }
    }
    __syncthreads();
    const int cnt = (scnt < MAXP) ? scnt : MAXP;

    // ---- Phase 2: per-pixel-pair top-K over half the survivors each ----
    float zk[K];   // ascending (z, idx)
    float dk[K];
    int   ik[K];
#pragma unroll
    for (int k = 0; k < K; ++k) { zk[k] = BIGF; dk[k] = -1.0f; ik[k] = 0x7fffffff; }

#pragma unroll 2
    for (int j = half; j < cnt; j += 2) {
        const float4 q = sp[j];           // 2-address broadcast, conflict-free
        const float dx = ndcx - q.x;
        const float dy = ndcy - q.y;
        const float dx2 = dx * dx;
        const float dy2 = dy * dy;
        const float d2 = dy2 + dx2;       // identical expression to ref/r1
        if (d2 < R2 && q.z > 0.0f) {
            const int pi = __float_as_int(q.w);
            if (q.z < zk[K - 1] || (q.z == zk[K - 1] && pi < ik[K - 1])) {
                float zi = q.z, di = d2;
                int   pj = pi;
#pragma unroll
                for (int k = 0; k < K; ++k) {
                    const bool lt = (zi < zk[k]) || (zi == zk[k] && pj < ik[k]);
                    if (lt) {
                        float t;
                        t = zk[k]; zk[k] = zi; zi = t;
                        t = dk[k]; dk[k] = di; di = t;
                        int ti = ik[k]; ik[k] = pj; pj = ti;
                    }
                }
            }
        }
    }

    // ---- merge: exchange partner list via same-wave shuffles, insert ----
    float pzk[K], pdk[K];
    int   pik[K];
#pragma unroll
    for (int k = 0; k < K; ++k) {
        pzk[k] = __shfl_xor(zk[k], 1);
        pdk[k] = __shfl_xor(dk[k], 1);
        pik[k] = __shfl_xor(ik[k], 1);
    }
#pragma unroll
    for (int m = 0; m < K; ++m) {
        float zi = pzk[m], di = pdk[m];
        int   pj = pik[m];
        // empty partner slots (BIGF, INT_MAX) are rejected by lex compare
        if (zi < zk[K - 1] || (zi == zk[K - 1] && pj < ik[K - 1])) {
#pragma unroll
            for (int k = 0; k < K; ++k) {
                const bool lt = (zi < zk[k]) || (zi == zk[k] && pj < ik[k]);
                if (lt) {
                    float t;
                    t = zk[k]; zk[k] = zi; zi = t;
                    t = dk[k]; dk[k] = di; di = t;
                    int ti = ik[k]; ik[k] = pj; pj = ti;
                }
            }
        }
    }
    // both threads of a pair now hold the identical union top-K

    // mask invalid slots
    float zb[K];
    float ib[K];
#pragma unroll
    for (int k = 0; k < K; ++k) {
        const bool v = zk[k] < BIGF;
        zb[k] = v ? zk[k] : -1.0f;
        ib[k] = v ? (float)ik[k] : -1.0f;
    }

    // ---- write float32 outputs: [idx | zbuf | dists], split across pair ----
    const int pid = n * (S * S) + h * S + w;
    float4* o = reinterpret_cast<float4*>(out);
    const int c4 = (npix * K) >> 2;   // float4 stride between sections
    const int q = pid * 2;

    if (half == 0) {
        o[q]     = make_float4(ib[0], ib[1], ib[2], ib[3]);
        o[q + 1] = make_float4(ib[4], ib[5], ib[6], ib[7]);
        o[c4 + q] = make_float4(zb[0], zb[1], zb[2], zb[3]);
    } else {
        o[c4 + q + 1] = make_float4(zb[4], zb[5], zb[6], zb[7]);
        o[2 * c4 + q]     = make_float4(dk[0], dk[1], dk[2], dk[3]);
        o[2 * c4 + q + 1] = make_float4(dk[4], dk[5], dk[6], dk[7]);
    }
}

extern "C" void kernel_launch(void* const* d_in, const int* in_sizes, int n_in,
                              void* d_out, int out_size, void* d_ws, size_t ws_size,
                              hipStream_t stream) {
    const float* pts = (const float*)d_in[0];
    float* out = (float*)d_out;

    const int N = in_sizes[0] / (3 * P);   // = 2
    const int npix = N * S * S;            // 32768

    const int grid = N * 128;              // 128 tiles per image -> 256 blocks
    hipLaunchKernelGGL(raster_paired, dim3(grid), dim3(BLK), 0, stream,
                       pts, out, npix);
}